// Round 5
// baseline (3336.431 us; speedup 1.0000x reference)
//
#include <hip/hip_runtime.h>
#include <math.h>

// ---------------------------------------------------------------------------
// GCNRecommender: 3x GCNConv (D=64) + linear head. N=300K nodes, E=1.2M edges.
// R9: R6/R7/R8 all spilled -- register-resident in-flight loads are a dead end
// on this compiler (3x scratch, VGPR cap hits). New k_gemm uses the HW path
// for in-flight bytes: __builtin_amdgcn_global_load_lds (DMA global->LDS, no
// VGPR cost), T3 "2-phase" pipeline: STAGE(next tile) -> compute(cur) ->
// __syncthreads (drains vmcnt; DMA latency hidden under ~2600cyc compute).
// Tile = 96 rows x 64 cols (24KB); dbuf 2x24 + W 16 = 64KB LDS, 2 blocks/CU,
// 512 persistent blocks grid-striding 3125 tiles (96*3125 = 300000 exactly).
// Model: LDS-pipe-bound ~108 cyc/row -> ~53us/GEMM (was 76). Gather/CSR
// unchanged (R6 form). All fp32.
// ---------------------------------------------------------------------------

// ---- CSR build -------------------------------------------------------------

__global__ void k_hist(const int* __restrict__ col, int* __restrict__ cnt, int e) {
    int i = blockIdx.x * blockDim.x + threadIdx.x;
    if (i < e) atomicAdd(&cnt[col[i]], 1);
}

// exclusive scan, 1024 elems/block (256 thr x 4)
__global__ void k_scan1(const int* __restrict__ cnt, int* __restrict__ offs,
                        int* __restrict__ bsum, int n) {
    __shared__ int s[256];
    const int t = threadIdx.x;
    const int base = blockIdx.x * 1024 + t * 4;
    int v[4], sum = 0;
    #pragma unroll
    for (int k = 0; k < 4; ++k) {
        v[k] = (base + k < n) ? cnt[base + k] : 0;
        sum += v[k];
    }
    s[t] = sum;
    __syncthreads();
    #pragma unroll
    for (int off = 1; off < 256; off <<= 1) {
        int x = (t >= off) ? s[t - off] : 0;
        __syncthreads();
        s[t] += x;
        __syncthreads();
    }
    int run = s[t] - sum;
    #pragma unroll
    for (int k = 0; k < 4; ++k) {
        if (base + k < n) offs[base + k] = run;
        run += v[k];
    }
    if (t == 255) bsum[blockIdx.x] = s[255];
}

__global__ void k_scan2(int* __restrict__ bsum, int nb) {
    __shared__ int s[512];
    const int t = threadIdx.x;
    int v = (t < nb) ? bsum[t] : 0;
    s[t] = v;
    __syncthreads();
    #pragma unroll
    for (int off = 1; off < 512; off <<= 1) {
        int x = (t >= off) ? s[t - off] : 0;
        __syncthreads();
        s[t] += x;
        __syncthreads();
    }
    if (t < nb) bsum[t] = s[t] - v;
}

__global__ void k_scan3(int* __restrict__ offs, const int* __restrict__ bsum,
                        int n, int e) {
    int i = blockIdx.x * blockDim.x + threadIdx.x;
    if (i < n) offs[i] += bsum[i >> 10];
    if (i == 0) offs[n] = e;
}

__global__ void k_fill(const int* __restrict__ row, const int* __restrict__ col,
                       const int* __restrict__ offs, int* __restrict__ cur,
                       int* __restrict__ elist, int e) {
    int i = blockIdx.x * blockDim.x + threadIdx.x;
    if (i < e) {
        int c = col[i];
        int pos = offs[c] + atomicAdd(&cur[c], 1);
        elist[pos] = row[i];
    }
}

__global__ void k_dinv(const int* __restrict__ cnt, float* __restrict__ dinv, int n) {
    int i = blockIdx.x * blockDim.x + threadIdx.x;
    if (i < n) dinv[i] = 1.0f / sqrtf((float)(cnt[i] + 1));  // +1 self-loop
}

// ---- async global->LDS (16B per lane per call; dest = wave base + lane*16) --
__device__ __forceinline__ void gl_lds16(const float* g, float* l) {
    __builtin_amdgcn_global_load_lds(
        (const __attribute__((address_space(1))) void*)g,
        (__attribute__((address_space(3))) void*)l,
        16, 0, 0);
}

// ---- GEMM: Y[r,:] = X[r,:] @ W ---------------------------------------------
// X source: (ut!=null) ? embedding tables (conv1) : dense X.
// Persistent blocks; each handles tiles b, b+gstride, ... Tile = 96 rows.
// Per iter: DMA-stage next tile into the other LDS buffer (8 gl_lds16/thread,
// zero VGPR), compute current tile from LDS, __syncthreads (vmcnt drain --
// latency fully covered by the ~2600cyc compute). Thread (cg=t&15,
// rbase=t>>4) computes rows rbase+16j (j=0..5), cols cg*4..cg*4+3.
// Epilogue: dinv!=null -> Y = dinv[row]*y (conv; bias+relu in gather)
//           dinv==null -> Y = y + bias   (linear head)

#define TROWS 96   // rows per tile (96*64 fp32 = 24KB; 16*6 rows: j=0..5)

__device__ __forceinline__ void stage_tile(
        float* dst,                                   // LDS buffer base
        const float* __restrict__ X,
        const int* __restrict__ uid, const int* __restrict__ iid,
        const float* __restrict__ ut, const float* __restrict__ it,
        int tile, int n, int u, int t) {
    if (ut != nullptr) {
        #pragma unroll
        for (int s = 0; s < 6; ++s) {                 // 6*256 = 1536 float4
            int idx = s * 256 + t;                    // float4 index in tile
            int row = tile * TROWS + (idx >> 4);
            int rc = min(row, n - 1);
            int cgi = idx & 15;
            const float* gsrc = (rc < u)
                ? (ut + (size_t)uid[rc] * 64 + cgi * 4)
                : (it + (size_t)iid[rc - u] * 64 + cgi * 4);
            gl_lds16(gsrc, dst + (size_t)idx * 4);
        }
    } else {
        const size_t mx = (size_t)n * 64 - 4;
        #pragma unroll
        for (int s = 0; s < 6; ++s) {
            int idx = s * 256 + t;
            size_t off = (size_t)tile * (TROWS * 64) + (size_t)idx * 4;
            if (off > mx) off = mx;                   // tail clamp (unused rows)
            gl_lds16(X + off, dst + (size_t)idx * 4);
        }
    }
}

#define FMA4(xr, a)                                                          \
    a.x = fmaf(xr.x, w0.x, a.x); a.y = fmaf(xr.x, w0.y, a.y);                \
    a.z = fmaf(xr.x, w0.z, a.z); a.w = fmaf(xr.x, w0.w, a.w);                \
    a.x = fmaf(xr.y, w1.x, a.x); a.y = fmaf(xr.y, w1.y, a.y);                \
    a.z = fmaf(xr.y, w1.z, a.z); a.w = fmaf(xr.y, w1.w, a.w);                \
    a.x = fmaf(xr.z, w2.x, a.x); a.y = fmaf(xr.z, w2.y, a.y);                \
    a.z = fmaf(xr.z, w2.z, a.z); a.w = fmaf(xr.z, w2.w, a.w);                \
    a.x = fmaf(xr.w, w3.x, a.x); a.y = fmaf(xr.w, w3.y, a.y);                \
    a.z = fmaf(xr.w, w3.z, a.z); a.w = fmaf(xr.w, w3.w, a.w);

__launch_bounds__(256, 2)
__global__ void k_gemm(const float* __restrict__ X,
                       const int* __restrict__ uid, const int* __restrict__ iid,
                       const float* __restrict__ ut, const float* __restrict__ it,
                       const float* __restrict__ W, const float* __restrict__ bias,
                       float* __restrict__ Y, const float* __restrict__ dinv,
                       int n, int u, int ntiles, int gstride) {
    __shared__ __align__(16) float Ws[64 * 64];       // 16 KB
    __shared__ __align__(16) float Xs[2][TROWS * 64]; // 2 x 24 KB
    const int t = threadIdx.x;

    const float4* W4 = (const float4*)W;
    float4* Ws4 = (float4*)Ws;
    #pragma unroll
    for (int idx = t; idx < 1024; idx += 256) Ws4[idx] = W4[idx];

    const int cg = t & 15;     // float4 col group
    const int rbase = t >> 4;  // rows rbase+16j within tile

    int tile = blockIdx.x;
    if (tile >= ntiles) return;                       // whole block uniform

    stage_tile(Xs[0], X, uid, iid, ut, it, tile, n, u, t);
    __syncthreads();                                  // W + first tile ready
    int cur = 0;

    const float4* b4 = (const float4*)bias;
    for (;;) {
        const int nxt = tile + gstride;
        if (nxt < ntiles)
            stage_tile(Xs[cur ^ 1], X, uid, iid, ut, it, nxt, n, u, t);

        // ---- compute current tile ----
        const float4* Xb4 = (const float4*)Xs[cur];
        float4 acc0 = make_float4(0.f, 0.f, 0.f, 0.f);
        float4 acc1 = make_float4(0.f, 0.f, 0.f, 0.f);
        float4 acc2 = make_float4(0.f, 0.f, 0.f, 0.f);
        float4 acc3 = make_float4(0.f, 0.f, 0.f, 0.f);
        float4 acc4 = make_float4(0.f, 0.f, 0.f, 0.f);
        float4 acc5 = make_float4(0.f, 0.f, 0.f, 0.f);
        #pragma unroll
        for (int kg = 0; kg < 16; ++kg) {
            float4 w0 = Ws4[(4 * kg + 0) * 16 + cg];
            float4 w1 = Ws4[(4 * kg + 1) * 16 + cg];
            float4 w2 = Ws4[(4 * kg + 2) * 16 + cg];
            float4 w3 = Ws4[(4 * kg + 3) * 16 + cg];
            float4 x0 = Xb4[(rbase +  0) * 16 + kg];
            float4 x1 = Xb4[(rbase + 16) * 16 + kg];
            float4 x2 = Xb4[(rbase + 32) * 16 + kg];
            float4 x3 = Xb4[(rbase + 48) * 16 + kg];
            float4 x4 = Xb4[(rbase + 64) * 16 + kg];
            float4 x5 = Xb4[(rbase + 80) * 16 + kg];
            FMA4(x0, acc0) FMA4(x1, acc1) FMA4(x2, acc2)
            FMA4(x3, acc3) FMA4(x4, acc4) FMA4(x5, acc5)
        }

        const int rb = tile * TROWS;
#define EPI(ACC, J)                                                          \
        {                                                                    \
            int row = rb + rbase + 16 * (J);                                 \
            if (row < n) {                                                   \
                float4 y = ACC;                                              \
                if (dinv != nullptr) {                                       \
                    float s = dinv[row];                                     \
                    y.x *= s; y.y *= s; y.z *= s; y.w *= s;                  \
                } else {                                                     \
                    float4 bb = b4[cg];                                      \
                    y.x += bb.x; y.y += bb.y; y.z += bb.z; y.w += bb.w;      \
                }                                                            \
                ((float4*)Y)[(size_t)row * 16 + cg] = y;                     \
            }                                                                \
        }
        EPI(acc0, 0) EPI(acc1, 1) EPI(acc2, 2)
        EPI(acc3, 3) EPI(acc4, 4) EPI(acc5, 5)
#undef EPI

        __syncthreads();   // drains prefetch DMA (covered by compute) + barrier
        if (nxt >= ntiles) break;
        tile = nxt;
        cur ^= 1;
    }
}

// ---- gather: 16 lanes per node (4 nodes/wave, 16 nodes/block).
// OUT[c,:] = f( dinv[c] * (sum_{r in in(c)} Yn[r,:] + Yn[c,:]) + b ),
// f = relu (conv1/conv2 outputs) or identity (conv3 output).
// Neighbor loop unrolled x4: 4 independent row loads in flight.
__launch_bounds__(256)
__global__ void k_gather(const int* __restrict__ offs, const int* __restrict__ elist,
                         const float* __restrict__ dinv, const float4* __restrict__ Yn4,
                         const float4* __restrict__ b4, float4* __restrict__ OUT4,
                         int n, int relu_out) {
    const int t = threadIdx.x;
    const int nid = blockIdx.x * 16 + (t >> 4);  // this 16-lane group's node
    const int q = t & 15;                        // float4 column group
    const int gbase = t & 48;                    // first lane of this group
    if (nid >= n) return;

    const int beg = offs[nid];
    const int end = offs[nid + 1];
    const int deg = end - beg;

    // Issue independent loads early: self row, dinv, bias, first 16 edge idx.
    float4 self = Yn4[(size_t)nid * 16 + q];
    float dc = dinv[nid];
    float4 bb = b4[q];
    int eidx = (q < deg) ? elist[beg + q] : 0;   // safe default row 0

    // wave-wide max degree (groups diverge only in predicates, not trip count)
    int m = deg;
    m = max(m, __shfl_xor(m, 16, 64));
    m = max(m, __shfl_xor(m, 32, 64));
    m = min(m, 16);

    float4 acc = make_float4(0.f, 0.f, 0.f, 0.f);
    int j = 0;
    for (; j + 4 <= m; j += 4) {
        int r0 = __shfl(eidx, gbase + j + 0, 64);
        int r1 = __shfl(eidx, gbase + j + 1, 64);
        int r2 = __shfl(eidx, gbase + j + 2, 64);
        int r3 = __shfl(eidx, gbase + j + 3, 64);
        float4 v0 = Yn4[(size_t)r0 * 16 + q];    // 4 loads in flight
        float4 v1 = Yn4[(size_t)r1 * 16 + q];
        float4 v2 = Yn4[(size_t)r2 * 16 + q];
        float4 v3 = Yn4[(size_t)r3 * 16 + q];
        if (j + 0 < deg) { acc.x += v0.x; acc.y += v0.y; acc.z += v0.z; acc.w += v0.w; }
        if (j + 1 < deg) { acc.x += v1.x; acc.y += v1.y; acc.z += v1.z; acc.w += v1.w; }
        if (j + 2 < deg) { acc.x += v2.x; acc.y += v2.y; acc.z += v2.z; acc.w += v2.w; }
        if (j + 3 < deg) { acc.x += v3.x; acc.y += v3.y; acc.z += v3.z; acc.w += v3.w; }
    }
    for (; j < m; ++j) {
        int r = __shfl(eidx, gbase + j, 64);
        float4 v = Yn4[(size_t)r * 16 + q];
        if (j < deg) { acc.x += v.x; acc.y += v.y; acc.z += v.z; acc.w += v.w; }
    }
    // rare tail (deg > 16): ~0 nodes for Poisson(4), correctness only
    for (int jj = beg + 16; jj < end; ++jj) {
        int r = elist[jj];
        float4 v = Yn4[(size_t)r * 16 + q];
        acc.x += v.x; acc.y += v.y; acc.z += v.z; acc.w += v.w;
    }

    float4 o;
    o.x = fmaf(dc, acc.x + self.x, bb.x);
    o.y = fmaf(dc, acc.y + self.y, bb.y);
    o.z = fmaf(dc, acc.z + self.z, bb.z);
    o.w = fmaf(dc, acc.w + self.w, bb.w);
    if (relu_out) {
        o.x = fmaxf(o.x, 0.f); o.y = fmaxf(o.y, 0.f);
        o.z = fmaxf(o.z, 0.f); o.w = fmaxf(o.w, 0.f);
    }
    OUT4[(size_t)nid * 16 + q] = o;
}

// ---------------------------------------------------------------------------

extern "C" void kernel_launch(void* const* d_in, const int* in_sizes, int n_in,
                              void* d_out, int out_size, void* d_ws, size_t ws_size,
                              hipStream_t stream) {
    const int*   user_ids = (const int*)d_in[0];
    const int*   item_ids = (const int*)d_in[1];
    const int*   edge     = (const int*)d_in[2];
    const float* ut   = (const float*)d_in[4];
    const float* it   = (const float*)d_in[5];
    const float* W1   = (const float*)d_in[6];
    const float* b1   = (const float*)d_in[7];
    const float* W2   = (const float*)d_in[8];
    const float* b2   = (const float*)d_in[9];
    const float* W3   = (const float*)d_in[10];
    const float* b3   = (const float*)d_in[11];
    const float* linW = (const float*)d_in[12];
    const float* linb = (const float*)d_in[13];

    const int u = in_sizes[0];
    const int iN = in_sizes[1];
    const int e = in_sizes[2] / 2;
    const int n = u + iN;

    // workspace layout
    float* A    = (float*)d_ws;                       // [n,64] node features
    float* dinv = A + (size_t)n * 64;                 // [n]
    int*   cnt  = (int*)(dinv + n);                   // [n]  (reused as cursor)
    int*   offs = cnt + n;                            // [n+1]
    int*   bsum = offs + n + 1;                       // [nb]
    int*   elist = bsum + 1024;                       // [e]
    float* Yn   = (float*)d_out;                      // [n,64] scratch; final out

    const int* erow = edge;
    const int* ecol = edge + e;

    const int B = 256;
    const int nb = (n + 1023) / 1024;

    // ---- CSR build + dinv ----
    hipMemsetAsync(cnt, 0, (size_t)n * sizeof(int), stream);
    k_hist<<<(e + B - 1) / B, B, 0, stream>>>(ecol, cnt, e);
    k_scan1<<<nb, 256, 0, stream>>>(cnt, offs, bsum, n);
    k_scan2<<<1, 512, 0, stream>>>(bsum, nb);
    k_scan3<<<(n + B - 1) / B, B, 0, stream>>>(offs, bsum, n, e);
    k_dinv<<<(n + B - 1) / B, B, 0, stream>>>(cnt, dinv, n);
    hipMemsetAsync(cnt, 0, (size_t)n * sizeof(int), stream);  // cursor
    k_fill<<<(e + B - 1) / B, B, 0, stream>>>(erow, ecol, offs, cnt, elist, e);

    const int ntiles = (n + TROWS - 1) / TROWS;       // 3125 for n=300000
    const int ggrid  = ntiles < 512 ? ntiles : 512;   // 2 blocks/CU resident
    const int gath_grid = (n + 15) / 16;              // 16 nodes/block

    // conv1 (embed fused into DMA staging)
    k_gemm<<<ggrid, B, 0, stream>>>(nullptr, user_ids, item_ids, ut, it,
                                    W1, nullptr, Yn, dinv, n, u, ntiles, ggrid);
    k_gather<<<gath_grid, B, 0, stream>>>(offs, elist, dinv, (const float4*)Yn,
                                          (const float4*)b1, (float4*)A, n, 1);
    // conv2 (relu applied at gather1 store)
    k_gemm<<<ggrid, B, 0, stream>>>(A, nullptr, nullptr, nullptr, nullptr,
                                    W2, nullptr, Yn, dinv, n, u, ntiles, ggrid);
    k_gather<<<gath_grid, B, 0, stream>>>(offs, elist, dinv, (const float4*)Yn,
                                          (const float4*)b2, (float4*)A, n, 1);
    // conv3
    k_gemm<<<ggrid, B, 0, stream>>>(A, nullptr, nullptr, nullptr, nullptr,
                                    W3, nullptr, Yn, dinv, n, u, ntiles, ggrid);
    k_gather<<<gath_grid, B, 0, stream>>>(offs, elist, dinv, (const float4*)Yn,
                                          (const float4*)b3, (float4*)A, n, 0);
    // mean-pool = identity; linear head -> d_out
    k_gemm<<<ggrid, B, 0, stream>>>(A, nullptr, nullptr, nullptr, nullptr,
                                    linW, linb, (float*)d_out, nullptr, n, u, ntiles, ggrid);
}

// Round 6
// 664.791 us; speedup vs baseline: 5.0188x; 5.0188x over previous
//
#include <hip/hip_runtime.h>
#include <math.h>

// ---------------------------------------------------------------------------
// GCNRecommender: 3x GCNConv (D=64) + linear head. N=300K nodes, E=1.2M edges.
// R10: R6-R9 all spilled (VGPR pinned at cap, GB-scale scratch). Root cause:
// unbounded scheduler hoisting windows under a tight VGPR cap. This version
// combines the two PROVEN-clean pieces: R0's padded stride-68 LDS layout +
// "#pragma unroll 2" compute (measured VGPR 52, 0 conflicts, no spill) with
// T14 reg-staged double-buffering for overlap: issue 6 NAMED float4 loads for
// tile t+1 -> compute tile t (ds_read+FMA) -> ds_write the regs to the other
// buffer (vmcnt wait lands here, covered by ~2500cyc compute) -> ONE barrier.
// Tile = 96 rows (n = 96*3125 exactly); LDS = 16K W + 2*26K X = 67KB,
// 2 blocks/CU, 512 persistent blocks. Model: ~40-50us/GEMM (was 76).
// Gather/CSR unchanged. All fp32.
// ---------------------------------------------------------------------------

// ---- CSR build -------------------------------------------------------------

__global__ void k_hist(const int* __restrict__ col, int* __restrict__ cnt, int e) {
    int i = blockIdx.x * blockDim.x + threadIdx.x;
    if (i < e) atomicAdd(&cnt[col[i]], 1);
}

// exclusive scan, 1024 elems/block (256 thr x 4)
__global__ void k_scan1(const int* __restrict__ cnt, int* __restrict__ offs,
                        int* __restrict__ bsum, int n) {
    __shared__ int s[256];
    const int t = threadIdx.x;
    const int base = blockIdx.x * 1024 + t * 4;
    int v[4], sum = 0;
    #pragma unroll
    for (int k = 0; k < 4; ++k) {
        v[k] = (base + k < n) ? cnt[base + k] : 0;
        sum += v[k];
    }
    s[t] = sum;
    __syncthreads();
    #pragma unroll
    for (int off = 1; off < 256; off <<= 1) {
        int x = (t >= off) ? s[t - off] : 0;
        __syncthreads();
        s[t] += x;
        __syncthreads();
    }
    int run = s[t] - sum;
    #pragma unroll
    for (int k = 0; k < 4; ++k) {
        if (base + k < n) offs[base + k] = run;
        run += v[k];
    }
    if (t == 255) bsum[blockIdx.x] = s[255];
}

__global__ void k_scan2(int* __restrict__ bsum, int nb) {
    __shared__ int s[512];
    const int t = threadIdx.x;
    int v = (t < nb) ? bsum[t] : 0;
    s[t] = v;
    __syncthreads();
    #pragma unroll
    for (int off = 1; off < 512; off <<= 1) {
        int x = (t >= off) ? s[t - off] : 0;
        __syncthreads();
        s[t] += x;
        __syncthreads();
    }
    if (t < nb) bsum[t] = s[t] - v;
}

__global__ void k_scan3(int* __restrict__ offs, const int* __restrict__ bsum,
                        int n, int e) {
    int i = blockIdx.x * blockDim.x + threadIdx.x;
    if (i < n) offs[i] += bsum[i >> 10];
    if (i == 0) offs[n] = e;
}

__global__ void k_fill(const int* __restrict__ row, const int* __restrict__ col,
                       const int* __restrict__ offs, int* __restrict__ cur,
                       int* __restrict__ elist, int e) {
    int i = blockIdx.x * blockDim.x + threadIdx.x;
    if (i < e) {
        int c = col[i];
        int pos = offs[c] + atomicAdd(&cur[c], 1);
        elist[pos] = row[i];
    }
}

__global__ void k_dinv(const int* __restrict__ cnt, float* __restrict__ dinv, int n) {
    int i = blockIdx.x * blockDim.x + threadIdx.x;
    if (i < n) dinv[i] = 1.0f / sqrtf((float)(cnt[i] + 1));  // +1 self-loop
}

// ---- GEMM: Y[r,:] = X[r,:] @ W ---------------------------------------------
// X source: (ut!=null) ? embedding tables (conv1) : dense X.
// Persistent blocks over 96-row tiles. Per iteration:
//   1. issue 6 named float4 global loads for tile t+1 (24 VGPR payload)
//   2. compute tile t from LDS (stride-68 pad: conflict-free, R0-verified)
//   3. ds_write the 6 regs into the other buffer (vmcnt wait absorbed here)
//   4. ONE __syncthreads, flip buffers.
// Thread (cg=t&15, rbase=t>>4) computes rows rbase+16j (j=0..5), cols cg*4+..
// Epilogue: dinv!=null -> Y = dinv[row]*y (conv; bias+relu in gather)
//           dinv==null -> Y = y + bias   (linear head)

#define TROWS 96
#define XSTR  68   // floats; +4 pad => conflict-free reads/writes (R0-measured)

__device__ __forceinline__ float4 ldx(const float* __restrict__ X,
                                      const int* __restrict__ uid,
                                      const int* __restrict__ iid,
                                      const float* __restrict__ ut,
                                      const float* __restrict__ it,
                                      int tile, int s, int srow, int scol,
                                      int n, int u) {
    int row = tile * TROWS + s * 16 + srow;
    int rc = min(row, n - 1);                 // clamp: duplicate loads harmless
    const float* src;
    if (ut != nullptr)
        src = (rc < u) ? (ut + (size_t)uid[rc] * 64)
                       : (it + (size_t)iid[rc - u] * 64);
    else
        src = X + (size_t)rc * 64;
    return *(const float4*)(src + scol * 4);
}

#define FMA4(xr, a)                                                          \
    a.x = fmaf(xr.x, w0.x, a.x); a.y = fmaf(xr.x, w0.y, a.y);                \
    a.z = fmaf(xr.x, w0.z, a.z); a.w = fmaf(xr.x, w0.w, a.w);                \
    a.x = fmaf(xr.y, w1.x, a.x); a.y = fmaf(xr.y, w1.y, a.y);                \
    a.z = fmaf(xr.y, w1.z, a.z); a.w = fmaf(xr.y, w1.w, a.w);                \
    a.x = fmaf(xr.z, w2.x, a.x); a.y = fmaf(xr.z, w2.y, a.y);                \
    a.z = fmaf(xr.z, w2.z, a.z); a.w = fmaf(xr.z, w2.w, a.w);                \
    a.x = fmaf(xr.w, w3.x, a.x); a.y = fmaf(xr.w, w3.y, a.y);                \
    a.z = fmaf(xr.w, w3.z, a.z); a.w = fmaf(xr.w, w3.w, a.w);

__launch_bounds__(256, 2)
__global__ void k_gemm(const float* __restrict__ X,
                       const int* __restrict__ uid, const int* __restrict__ iid,
                       const float* __restrict__ ut, const float* __restrict__ it,
                       const float* __restrict__ W, const float* __restrict__ bias,
                       float* __restrict__ Y, const float* __restrict__ dinv,
                       int n, int u, int ntiles, int gstride) {
    __shared__ __align__(16) float Ws[64 * 64];        // 16 KB
    __shared__ __align__(16) float Xs[2][TROWS * XSTR]; // 2 x 25.5 KB
    const int t = threadIdx.x;

    const float4* W4 = (const float4*)W;
    float4* Ws4 = (float4*)Ws;
    for (int idx = t; idx < 1024; idx += 256) Ws4[idx] = W4[idx];

    const int cg   = t & 15;   // col group (both compute and staging)
    const int rbse = t >> 4;   // row base (both compute and staging)

    int tile = blockIdx.x;
    if (tile >= ntiles) return;            // uniform per block

    float4 g0, g1, g2, g3, g4, g5;

#define STAGE_LOAD(T)                                                        \
    g0 = ldx(X, uid, iid, ut, it, (T), 0, rbse, cg, n, u);                   \
    g1 = ldx(X, uid, iid, ut, it, (T), 1, rbse, cg, n, u);                   \
    g2 = ldx(X, uid, iid, ut, it, (T), 2, rbse, cg, n, u);                   \
    g3 = ldx(X, uid, iid, ut, it, (T), 3, rbse, cg, n, u);                   \
    g4 = ldx(X, uid, iid, ut, it, (T), 4, rbse, cg, n, u);                   \
    g5 = ldx(X, uid, iid, ut, it, (T), 5, rbse, cg, n, u);

#define STAGE_WRITE(B)                                                       \
    {                                                                        \
        float* xb = Xs[B];                                                   \
        *(float4*)&xb[(0 * 16 + rbse) * XSTR + cg * 4] = g0;                 \
        *(float4*)&xb[(1 * 16 + rbse) * XSTR + cg * 4] = g1;                 \
        *(float4*)&xb[(2 * 16 + rbse) * XSTR + cg * 4] = g2;                 \
        *(float4*)&xb[(3 * 16 + rbse) * XSTR + cg * 4] = g3;                 \
        *(float4*)&xb[(4 * 16 + rbse) * XSTR + cg * 4] = g4;                 \
        *(float4*)&xb[(5 * 16 + rbse) * XSTR + cg * 4] = g5;                 \
    }

    // prologue: tile 0 into buf 0
    STAGE_LOAD(tile)
    STAGE_WRITE(0)
    __syncthreads();
    int cur = 0;

    const float4* b4 = (const float4*)bias;
    for (;;) {
        const int nxt = tile + gstride;
        const bool has_next = (nxt < ntiles);
        if (has_next) { STAGE_LOAD(nxt) }   // loads in flight during compute

        // ---- compute current tile from Xs[cur] ----
        const float* xb = Xs[cur];
        float4 acc0 = make_float4(0.f, 0.f, 0.f, 0.f);
        float4 acc1 = make_float4(0.f, 0.f, 0.f, 0.f);
        float4 acc2 = make_float4(0.f, 0.f, 0.f, 0.f);
        float4 acc3 = make_float4(0.f, 0.f, 0.f, 0.f);
        float4 acc4 = make_float4(0.f, 0.f, 0.f, 0.f);
        float4 acc5 = make_float4(0.f, 0.f, 0.f, 0.f);
        #pragma unroll 2
        for (int kg = 0; kg < 16; ++kg) {
            float4 w0 = Ws4[(4 * kg + 0) * 16 + cg];
            float4 w1 = Ws4[(4 * kg + 1) * 16 + cg];
            float4 w2 = Ws4[(4 * kg + 2) * 16 + cg];
            float4 w3 = Ws4[(4 * kg + 3) * 16 + cg];
            float4 x0 = *(const float4*)&xb[(rbse +  0) * XSTR + kg * 4];
            float4 x1 = *(const float4*)&xb[(rbse + 16) * XSTR + kg * 4];
            float4 x2 = *(const float4*)&xb[(rbse + 32) * XSTR + kg * 4];
            float4 x3 = *(const float4*)&xb[(rbse + 48) * XSTR + kg * 4];
            float4 x4 = *(const float4*)&xb[(rbse + 64) * XSTR + kg * 4];
            float4 x5 = *(const float4*)&xb[(rbse + 80) * XSTR + kg * 4];
            FMA4(x0, acc0) FMA4(x1, acc1) FMA4(x2, acc2)
            FMA4(x3, acc3) FMA4(x4, acc4) FMA4(x5, acc5)
        }

        const int rb = tile * TROWS;
#define EPI(ACC, J)                                                          \
        {                                                                    \
            int row = rb + rbse + 16 * (J);                                  \
            if (row < n) {                                                   \
                float4 y = ACC;                                              \
                if (dinv != nullptr) {                                       \
                    float s = dinv[row];                                     \
                    y.x *= s; y.y *= s; y.z *= s; y.w *= s;                  \
                } else {                                                     \
                    float4 bb = b4[cg];                                      \
                    y.x += bb.x; y.y += bb.y; y.z += bb.z; y.w += bb.w;      \
                }                                                            \
                ((float4*)Y)[(size_t)row * 16 + cg] = y;                     \
            }                                                                \
        }
        EPI(acc0, 0) EPI(acc1, 1) EPI(acc2, 2)
        EPI(acc3, 3) EPI(acc4, 4) EPI(acc5, 5)
#undef EPI

        if (!has_next) break;
        STAGE_WRITE(cur ^ 1)     // vmcnt wait lands here, covered by compute
        __syncthreads();         // writes visible; prev buffer reads all done
        tile = nxt;
        cur ^= 1;
    }
#undef STAGE_LOAD
#undef STAGE_WRITE
}

// ---- gather: 16 lanes per node (4 nodes/wave, 16 nodes/block).
// OUT[c,:] = f( dinv[c] * (sum_{r in in(c)} Yn[r,:] + Yn[c,:]) + b ),
// f = relu (conv1/conv2 outputs) or identity (conv3 output).
// Neighbor loop unrolled x4: 4 independent row loads in flight.
__launch_bounds__(256)
__global__ void k_gather(const int* __restrict__ offs, const int* __restrict__ elist,
                         const float* __restrict__ dinv, const float4* __restrict__ Yn4,
                         const float4* __restrict__ b4, float4* __restrict__ OUT4,
                         int n, int relu_out) {
    const int t = threadIdx.x;
    const int nid = blockIdx.x * 16 + (t >> 4);  // this 16-lane group's node
    const int q = t & 15;                        // float4 column group
    const int gbase = t & 48;                    // first lane of this group
    if (nid >= n) return;

    const int beg = offs[nid];
    const int end = offs[nid + 1];
    const int deg = end - beg;

    // Issue independent loads early: self row, dinv, bias, first 16 edge idx.
    float4 self = Yn4[(size_t)nid * 16 + q];
    float dc = dinv[nid];
    float4 bb = b4[q];
    int eidx = (q < deg) ? elist[beg + q] : 0;   // safe default row 0

    // wave-wide max degree (groups diverge only in predicates, not trip count)
    int m = deg;
    m = max(m, __shfl_xor(m, 16, 64));
    m = max(m, __shfl_xor(m, 32, 64));
    m = min(m, 16);

    float4 acc = make_float4(0.f, 0.f, 0.f, 0.f);
    int j = 0;
    for (; j + 4 <= m; j += 4) {
        int r0 = __shfl(eidx, gbase + j + 0, 64);
        int r1 = __shfl(eidx, gbase + j + 1, 64);
        int r2 = __shfl(eidx, gbase + j + 2, 64);
        int r3 = __shfl(eidx, gbase + j + 3, 64);
        float4 v0 = Yn4[(size_t)r0 * 16 + q];    // 4 loads in flight
        float4 v1 = Yn4[(size_t)r1 * 16 + q];
        float4 v2 = Yn4[(size_t)r2 * 16 + q];
        float4 v3 = Yn4[(size_t)r3 * 16 + q];
        if (j + 0 < deg) { acc.x += v0.x; acc.y += v0.y; acc.z += v0.z; acc.w += v0.w; }
        if (j + 1 < deg) { acc.x += v1.x; acc.y += v1.y; acc.z += v1.z; acc.w += v1.w; }
        if (j + 2 < deg) { acc.x += v2.x; acc.y += v2.y; acc.z += v2.z; acc.w += v2.w; }
        if (j + 3 < deg) { acc.x += v3.x; acc.y += v3.y; acc.z += v3.z; acc.w += v3.w; }
    }
    for (; j < m; ++j) {
        int r = __shfl(eidx, gbase + j, 64);
        float4 v = Yn4[(size_t)r * 16 + q];
        if (j < deg) { acc.x += v.x; acc.y += v.y; acc.z += v.z; acc.w += v.w; }
    }
    // rare tail (deg > 16): ~0 nodes for Poisson(4), correctness only
    for (int jj = beg + 16; jj < end; ++jj) {
        int r = elist[jj];
        float4 v = Yn4[(size_t)r * 16 + q];
        acc.x += v.x; acc.y += v.y; acc.z += v.z; acc.w += v.w;
    }

    float4 o;
    o.x = fmaf(dc, acc.x + self.x, bb.x);
    o.y = fmaf(dc, acc.y + self.y, bb.y);
    o.z = fmaf(dc, acc.z + self.z, bb.z);
    o.w = fmaf(dc, acc.w + self.w, bb.w);
    if (relu_out) {
        o.x = fmaxf(o.x, 0.f); o.y = fmaxf(o.y, 0.f);
        o.z = fmaxf(o.z, 0.f); o.w = fmaxf(o.w, 0.f);
    }
    OUT4[(size_t)nid * 16 + q] = o;
}

// ---------------------------------------------------------------------------

extern "C" void kernel_launch(void* const* d_in, const int* in_sizes, int n_in,
                              void* d_out, int out_size, void* d_ws, size_t ws_size,
                              hipStream_t stream) {
    const int*   user_ids = (const int*)d_in[0];
    const int*   item_ids = (const int*)d_in[1];
    const int*   edge     = (const int*)d_in[2];
    const float* ut   = (const float*)d_in[4];
    const float* it   = (const float*)d_in[5];
    const float* W1   = (const float*)d_in[6];
    const float* b1   = (const float*)d_in[7];
    const float* W2   = (const float*)d_in[8];
    const float* b2   = (const float*)d_in[9];
    const float* W3   = (const float*)d_in[10];
    const float* b3   = (const float*)d_in[11];
    const float* linW = (const float*)d_in[12];
    const float* linb = (const float*)d_in[13];

    const int u = in_sizes[0];
    const int iN = in_sizes[1];
    const int e = in_sizes[2] / 2;
    const int n = u + iN;

    // workspace layout
    float* A    = (float*)d_ws;                       // [n,64] node features
    float* dinv = A + (size_t)n * 64;                 // [n]
    int*   cnt  = (int*)(dinv + n);                   // [n]  (reused as cursor)
    int*   offs = cnt + n;                            // [n+1]
    int*   bsum = offs + n + 1;                       // [nb]
    int*   elist = bsum + 1024;                       // [e]
    float* Yn   = (float*)d_out;                      // [n,64] scratch; final out

    const int* erow = edge;
    const int* ecol = edge + e;

    const int B = 256;
    const int nb = (n + 1023) / 1024;

    // ---- CSR build + dinv ----
    hipMemsetAsync(cnt, 0, (size_t)n * sizeof(int), stream);
    k_hist<<<(e + B - 1) / B, B, 0, stream>>>(ecol, cnt, e);
    k_scan1<<<nb, 256, 0, stream>>>(cnt, offs, bsum, n);
    k_scan2<<<1, 512, 0, stream>>>(bsum, nb);
    k_scan3<<<(n + B - 1) / B, B, 0, stream>>>(offs, bsum, n, e);
    k_dinv<<<(n + B - 1) / B, B, 0, stream>>>(cnt, dinv, n);
    hipMemsetAsync(cnt, 0, (size_t)n * sizeof(int), stream);  // cursor
    k_fill<<<(e + B - 1) / B, B, 0, stream>>>(erow, ecol, offs, cnt, elist, e);

    const int ntiles = (n + TROWS - 1) / TROWS;       // 3125 for n=300000
    const int ggrid  = ntiles < 512 ? ntiles : 512;   // 2 blocks/CU resident
    const int gath_grid = (n + 15) / 16;              // 16 nodes/block

    // conv1 (embed fused into staging)
    k_gemm<<<ggrid, B, 0, stream>>>(nullptr, user_ids, item_ids, ut, it,
                                    W1, nullptr, Yn, dinv, n, u, ntiles, ggrid);
    k_gather<<<gath_grid, B, 0, stream>>>(offs, elist, dinv, (const float4*)Yn,
                                          (const float4*)b1, (float4*)A, n, 1);
    // conv2 (relu applied at gather1 store)
    k_gemm<<<ggrid, B, 0, stream>>>(A, nullptr, nullptr, nullptr, nullptr,
                                    W2, nullptr, Yn, dinv, n, u, ntiles, ggrid);
    k_gather<<<gath_grid, B, 0, stream>>>(offs, elist, dinv, (const float4*)Yn,
                                          (const float4*)b2, (float4*)A, n, 1);
    // conv3
    k_gemm<<<ggrid, B, 0, stream>>>(A, nullptr, nullptr, nullptr, nullptr,
                                    W3, nullptr, Yn, dinv, n, u, ntiles, ggrid);
    k_gather<<<gath_grid, B, 0, stream>>>(offs, elist, dinv, (const float4*)Yn,
                                          (const float4*)b3, (float4*)A, n, 0);
    // mean-pool = identity; linear head -> d_out
    k_gemm<<<ggrid, B, 0, stream>>>(A, nullptr, nullptr, nullptr, nullptr,
                                    linW, linb, (float*)d_out, nullptr, n, u, ntiles, ggrid);
}